// Round 1
// baseline (10149.270 us; speedup 1.0000x reference)
//
#include <hip/hip_runtime.h>
#include <hip/hip_bf16.h>
#include <cstdint>
#include <cstddef>

// Problem constants
#define V_ 50000
#define T_ 32
#define E_ 256
#define H_ 512
#define B_ 64
#define S_ 512
// combined GEMM K = E + H = 768, gates = 4H = 2048

typedef __attribute__((ext_vector_type(8))) short short8;
typedef __attribute__((ext_vector_type(4))) float f32x4;

__device__ __forceinline__ unsigned short f2b(float x){
  unsigned u = __float_as_uint(x);
  unsigned r = u + 0x7FFFu + ((u >> 16) & 1u);   // RNE
  return (unsigned short)(r >> 16);
}
__device__ __forceinline__ float b2f(unsigned short b){
  return __uint_as_float(((unsigned)b) << 16);
}
__device__ __forceinline__ float sigf(float x){
  return 1.f / (1.f + __expf(-x));
}
__device__ __forceinline__ float tanhfast(float x){
  return 1.f - 2.f / (__expf(2.f * x) + 1.f);
}

// ---------------- prep kernels ----------------

// Wc (2048 x 768) bf16 : [w_ih | w_hh] row-major per gate row
__global__ void prep_wc_kernel(const float* __restrict__ w_ih, const float* __restrict__ w_hh,
                               unsigned short* __restrict__ wc){
  int idx = blockIdx.x * 256 + threadIdx.x;
  if(idx >= 2048 * 768) return;
  int g = idx / 768, k = idx - g * 768;
  float v = (k < 256) ? w_ih[g * 256 + k] : w_hh[g * 512 + (k - 256)];
  wc[idx] = f2b(v);
}

// fcw_t [k][n]  (1024 x 32) bf16
__global__ void prep_fcw_kernel(const float* __restrict__ fc_w, unsigned short* __restrict__ fcw_t){
  int idx = blockIdx.x * 256 + threadIdx.x;   // 32768
  int k = idx >> 5, n = idx & 31;
  fcw_t[idx] = f2b(fc_w[n * 1024 + k]);
}

// gather embeddings -> bf16 (S, B, E)
__global__ void gather_kernel(const float* __restrict__ emb, const int* __restrict__ x,
                              unsigned short* __restrict__ e_bf){
  int tok = blockIdx.x;            // s*64 + b
  int s = tok >> 6, b = tok & 63;
  int row = x[b * 512 + s];
  int k = threadIdx.x;
  e_bf[(size_t)tok * 256 + k] = f2b(emb[(size_t)row * 256 + k]);
}

// zero c-state and the boundary h slots (slot 0 of hf, slot 512 of hb)
__global__ void init_kernel(float* __restrict__ c_buf,
                            unsigned short* __restrict__ hf_buf,
                            unsigned short* __restrict__ hb_buf){
  int idx = blockIdx.x * 256 + threadIdx.x;    // 65536 total
  c_buf[idx] = 0.f;
  if(idx < 32768){
    hf_buf[idx] = 0;
    hb_buf[(size_t)512 * 32768 + idx] = 0;
  }
}

// ---------------- LSTM step (both directions), one launch per time step ----------------
// grid = 64 blocks: blockIdx>>5 = dir (0 fwd, 1 bwd), blockIdx&31 = h-dim slice (16 dims)
// block = 256 threads = 4 waves; wave w = M-tile (batch rows 16w..16w+15)
// GEMM: A (64 x 768) = [e_t | h_prev] bf16,  B = Wc rows for 16 dims x 4 gate types
__global__ __launch_bounds__(256) void lstm_step_kernel(
    const unsigned short* __restrict__ e_bf,
    const unsigned short* __restrict__ Wc_f, const unsigned short* __restrict__ Wc_b,
    const float* __restrict__ b_f, const float* __restrict__ b_b,
    unsigned short* __restrict__ hf_buf, unsigned short* __restrict__ hb_buf,
    float* __restrict__ c_buf, int t)
{
  __shared__ __align__(16) unsigned short ldsA[2][64 * 128];
  __shared__ __align__(16) unsigned short ldsB[2][64 * 128];

  const int tid  = threadIdx.x;
  const int wid  = tid >> 6;
  const int lane = tid & 63;
  const int dir  = blockIdx.x >> 5;
  const int j0   = (blockIdx.x & 31) << 4;

  const unsigned short* Wc   = dir ? Wc_b : Wc_f;
  const float*          bias = dir ? b_b  : b_f;
  const unsigned short* hprev;
  unsigned short*       hout;
  float*                cst;
  int t_e;
  if(dir == 0){
    t_e   = t;
    hprev = hf_buf + (size_t)t * 32768;
    hout  = hf_buf + (size_t)(t + 1) * 32768;
    cst   = c_buf;
  } else {
    int tb = 511 - t;
    t_e   = tb;
    hprev = hb_buf + (size_t)(tb + 1) * 32768;
    hout  = hb_buf + (size_t)tb * 32768;
    cst   = c_buf + 32768;
  }

  uint4 ra[4], rb[4];

#define LOADC(kc)                                                                 \
  {                                                                               \
    _Pragma("unroll")                                                             \
    for(int i = 0; i < 4; i++){                                                   \
      int sid = tid + i * 256;                                                    \
      int row = sid >> 4, seg = sid & 15;                                         \
      const unsigned short* asrc;                                                 \
      if((kc) < 2) asrc = e_bf + (size_t)t_e * 16384 + row * 256 + (kc) * 128 + seg * 8; \
      else         asrc = hprev + (size_t)row * 512 + ((kc) - 2) * 128 + seg * 8; \
      ra[i] = *(const uint4*)asrc;                                                \
      int gg = ((row >> 4) << 9) + j0 + (row & 15);                               \
      rb[i] = *(const uint4*)(Wc + (size_t)gg * 768 + (kc) * 128 + seg * 8);      \
    }                                                                             \
  }

#define STOREC(bufi)                                                              \
  {                                                                               \
    _Pragma("unroll")                                                             \
    for(int i = 0; i < 4; i++){                                                   \
      int sid = tid + i * 256;                                                    \
      int row = sid >> 4, seg = sid & 15;                                         \
      int off = row * 128 + ((seg * 8) ^ ((row & 7) << 3));                       \
      *(uint4*)&ldsA[bufi][off] = ra[i];                                          \
      *(uint4*)&ldsB[bufi][off] = rb[i];                                          \
    }                                                                             \
  }

  f32x4 acc0 = {0.f,0.f,0.f,0.f}, acc1 = {0.f,0.f,0.f,0.f};
  f32x4 acc2 = {0.f,0.f,0.f,0.f}, acc3 = {0.f,0.f,0.f,0.f};

  LOADC(0); STOREC(0); __syncthreads();

  const int ra_row = wid * 16 + (lane & 15);
  const int r0     = (lane & 15);
  const int kbase  = (lane >> 4) * 8;
  const int swA    = (ra_row & 7) << 3;
  const int swB    = (r0 & 7) << 3;

  for(int kc = 0; kc < 6; kc++){
    int cur = kc & 1;
    if(kc < 5) LOADC(kc + 1);
#pragma unroll
    for(int ks = 0; ks < 4; ks++){
      int col = ks * 32 + kbase;
      short8 af = *(const short8*)&ldsA[cur][ra_row * 128 + (col ^ swA)];
      short8 bf0 = *(const short8*)&ldsB[cur][(r0     ) * 128 + (col ^ swB)];
      short8 bf1 = *(const short8*)&ldsB[cur][(16 + r0) * 128 + (col ^ swB)];
      short8 bf2 = *(const short8*)&ldsB[cur][(32 + r0) * 128 + (col ^ swB)];
      short8 bf3 = *(const short8*)&ldsB[cur][(48 + r0) * 128 + (col ^ swB)];
      acc0 = __builtin_amdgcn_mfma_f32_16x16x32_bf16(af, bf0, acc0, 0, 0, 0);
      acc1 = __builtin_amdgcn_mfma_f32_16x16x32_bf16(af, bf1, acc1, 0, 0, 0);
      acc2 = __builtin_amdgcn_mfma_f32_16x16x32_bf16(af, bf2, acc2, 0, 0, 0);
      acc3 = __builtin_amdgcn_mfma_f32_16x16x32_bf16(af, bf3, acc3, 0, 0, 0);
    }
    __syncthreads();
    if(kc < 5){ STOREC(1 - cur); __syncthreads(); }
  }

  // epilogue: gates -> c,h
  const int j = j0 + (lane & 15);
  const float bi = bias[j], bff = bias[512 + j], bg = bias[1024 + j], bo = bias[1536 + j];
#pragma unroll
  for(int r = 0; r < 4; r++){
    int b = wid * 16 + ((lane >> 4) << 2) + r;
    float ii = acc0[r] + bi;
    float ff = acc1[r] + bff;
    float gg = acc2[r] + bg;
    float oo = acc3[r] + bo;
    size_t ci = (size_t)b * 512 + j;
    float cn = sigf(ff) * cst[ci] + sigf(ii) * tanhfast(gg);
    cst[ci] = cn;
    hout[(size_t)b * 512 + j] = f2b(sigf(oo) * tanhfast(cn));
  }
#undef LOADC
#undef STOREC
}

// ---------------- emission logits: em[s][b][n] = [h_f|h_b] . fc_w[n] + fc_b[n] ----------------
__global__ __launch_bounds__(256) void em_kernel(
    const unsigned short* __restrict__ hf_buf, const unsigned short* __restrict__ hb_buf,
    const unsigned short* __restrict__ fcw_t, const float* __restrict__ fc_b,
    float* __restrict__ em)
{
  __shared__ __align__(16) unsigned short w[1024 * 32];
  __shared__ __align__(16) unsigned short hrow[8 * 1024];
  int tid = threadIdx.x;
#pragma unroll
  for(int i = 0; i < 16; i++){
    int idx = tid + i * 256;
    ((uint4*)w)[idx] = ((const uint4*)fcw_t)[idx];
  }
  __syncthreads();
  float fb = fc_b[tid & 31];
  for(int grp = 0; grp < 16; grp++){
    int tokbase = blockIdx.x * 128 + grp * 8;
#pragma unroll
    for(int i = 0; i < 4; i++){
      int sid = tid + i * 256;
      int rr = sid >> 7, seg = sid & 127;
      int tok = tokbase + rr, s = tok >> 6, b = tok & 63;
      const unsigned short* src = (seg < 64)
          ? hf_buf + ((size_t)(s + 1) * 64 + b) * 512 + seg * 8
          : hb_buf + ((size_t)s * 64 + b) * 512 + (seg - 64) * 8;
      ((uint4*)hrow)[sid] = *(const uint4*)src;
    }
    __syncthreads();
    int rr = tid >> 5, n = tid & 31;
    float acc = 0.f;
#pragma unroll 8
    for(int k = 0; k < 1024; k++)
      acc += b2f(hrow[rr * 1024 + k]) * b2f(w[k * 32 + n]);
    int tok = tokbase + rr, s = tok >> 6, b = tok & 63;
    em[((size_t)s * 64 + b) * 32 + n] = acc + fb;
    __syncthreads();
  }
}

// ---------------- CRF forward + path score, per batch element ----------------
__global__ __launch_bounds__(64) void crf_kernel(
    const float* __restrict__ em, const float* __restrict__ trans,
    const float* __restrict__ start_trans, const float* __restrict__ end_trans,
    const int* __restrict__ tags, float* __restrict__ llh)
{
  __shared__ float tr[32 * 32];
  __shared__ float al[2][32];
  __shared__ float red[64];
  int b = blockIdx.x, lane = threadIdx.x;
  for(int idx = lane; idx < 1024; idx += 64) tr[idx] = trans[idx];
  if(lane < 32) al[0][lane] = start_trans[lane] + em[(size_t)b * 32 + lane];
  __syncthreads();
  int cur = 0;
  for(int s = 1; s < 512; s++){
    if(lane < 32){
      float et = em[((size_t)s * 64 + b) * 32 + lane];
      float m = -1e30f;
#pragma unroll 8
      for(int t1 = 0; t1 < 32; t1++){
        float v = al[cur][t1] + tr[t1 * 32 + lane];
        m = fmaxf(m, v);
      }
      float sum = 0.f;
#pragma unroll 8
      for(int t1 = 0; t1 < 32; t1++)
        sum += __expf(al[cur][t1] + tr[t1 * 32 + lane] - m);
      al[cur ^ 1][lane] = m + __logf(sum) + et;
    }
    __syncthreads();
    cur ^= 1;
  }
  float den = 0.f;
  if(lane == 0){
    float m = -1e30f;
    for(int t2 = 0; t2 < 32; t2++) m = fmaxf(m, al[cur][t2] + end_trans[t2]);
    float sum = 0.f;
    for(int t2 = 0; t2 < 32; t2++) sum += __expf(al[cur][t2] + end_trans[t2] - m);
    den = m + __logf(sum);
  }
  float acc = 0.f;
  for(int s = lane; s < 512; s += 64){
    int tg = tags[b * 512 + s];
    acc += em[((size_t)s * 64 + b) * 32 + tg];
    if(s < 511){
      int tg2 = tags[b * 512 + s + 1];
      acc += trans[tg * 32 + tg2];
    }
  }
  red[lane] = acc;
  __syncthreads();
  if(lane == 0){
    float ns = 0.f;
    for(int i = 0; i < 64; i++) ns += red[i];
    float num = start_trans[tags[b * 512]] + ns + end_trans[tags[b * 512 + 511]];
    llh[b] = num - den;
  }
}

__global__ void final_kernel(const float* __restrict__ llh, float* __restrict__ out){
  __shared__ float red[64];
  int lane = threadIdx.x;
  red[lane] = llh[lane];
  __syncthreads();
  if(lane == 0){
    float s = 0.f;
    for(int i = 0; i < 64; i++) s += red[i];
    out[0] = -s / 64.f;
  }
}

extern "C" void kernel_launch(void* const* d_in, const int* in_sizes, int n_in,
                              void* d_out, int out_size, void* d_ws, size_t ws_size,
                              hipStream_t stream)
{
  const float* emb        = (const float*)d_in[0];
  const float* w_ih_f     = (const float*)d_in[1];
  const float* w_hh_f     = (const float*)d_in[2];
  const float* b_f        = (const float*)d_in[3];
  const float* w_ih_b     = (const float*)d_in[4];
  const float* w_hh_b     = (const float*)d_in[5];
  const float* b_b        = (const float*)d_in[6];
  const float* fc_w       = (const float*)d_in[7];
  const float* fc_b       = (const float*)d_in[8];
  const float* start_tr   = (const float*)d_in[9];
  const float* end_tr     = (const float*)d_in[10];
  const float* trans      = (const float*)d_in[11];
  const int*   x          = (const int*)d_in[12];
  const int*   tags       = (const int*)d_in[13];

  char* p = (char*)d_ws;
  unsigned short* e_bf   = (unsigned short*)p; p += (size_t)512 * 64 * 256 * 2;  // 16.8 MB
  unsigned short* Wc_f   = (unsigned short*)p; p += (size_t)2048 * 768 * 2;      // 3.1 MB
  unsigned short* Wc_b   = (unsigned short*)p; p += (size_t)2048 * 768 * 2;      // 3.1 MB
  unsigned short* fcw_t  = (unsigned short*)p; p += (size_t)1024 * 32 * 2;       // 64 KB
  unsigned short* hf_buf = (unsigned short*)p; p += (size_t)513 * 32768 * 2;     // 33.6 MB
  unsigned short* hb_buf = (unsigned short*)p; p += (size_t)513 * 32768 * 2;     // 33.6 MB
  float*          c_buf  = (float*)p;          p += (size_t)2 * 32768 * 4;       // 256 KB
  float*          em     = (float*)p;          p += (size_t)512 * 64 * 32 * 4;   // 4.2 MB
  float*          llh    = (float*)p;          p += 256;

  hipLaunchKernelGGL(prep_wc_kernel, dim3(6144), dim3(256), 0, stream, w_ih_f, w_hh_f, Wc_f);
  hipLaunchKernelGGL(prep_wc_kernel, dim3(6144), dim3(256), 0, stream, w_ih_b, w_hh_b, Wc_b);
  hipLaunchKernelGGL(prep_fcw_kernel, dim3(128), dim3(256), 0, stream, fc_w, fcw_t);
  hipLaunchKernelGGL(gather_kernel, dim3(32768), dim3(256), 0, stream, emb, x, e_bf);
  hipLaunchKernelGGL(init_kernel, dim3(256), dim3(256), 0, stream, c_buf, hf_buf, hb_buf);

  for(int t = 0; t < 512; t++){
    hipLaunchKernelGGL(lstm_step_kernel, dim3(64), dim3(256), 0, stream,
                       e_bf, Wc_f, Wc_b, b_f, b_b, hf_buf, hb_buf, c_buf, t);
  }

  hipLaunchKernelGGL(em_kernel, dim3(256), dim3(256), 0, stream, hf_buf, hb_buf, fcw_t, fc_b, em);
  hipLaunchKernelGGL(crf_kernel, dim3(64), dim3(64), 0, stream, em, trans, start_tr, end_tr, tags, llh);
  hipLaunchKernelGGL(final_kernel, dim3(1), dim3(64), 0, stream, llh, (float*)d_out);
}